// Round 2
// 284.613 us; speedup vs baseline: 1.0253x; 1.0253x over previous
//
#include <hip/hip_runtime.h>
#include <math.h>

#define HW 65536
#define BN 16

// ws layout (floats):
//   ws[0] : mask-loss sum,  ws[1] : skin-loss sum
//   per-b block of 9 at ws[2 + b*9]:
//     +0..2 : nocs msum,cnt,dsum  +3..5 : locmap  +6..8 : rotmap
//   per-(b,j) block of 7 at ws[38 + (b*16+j)*7]: S, Nloc0..2, Nrot0..2
// total = 38 + 64*7 = 486 floats

__device__ __forceinline__ float fsig(float x) {
    return __builtin_amdgcn_rcpf(1.0f + __expf(-x));
}
__device__ __forceinline__ float sq(float x) { return x * x; }

__device__ __forceinline__ float wred(float v) {
#pragma unroll
    for (int off = 32; off; off >>= 1) v += __shfl_xor(v, off, 64);
    return v;
}

// ---- Fused kernel: pixel losses + per-joint score sums, 1 px/thread ------
// grid (HW/256, 4) = 1024 blocks -> 4 blocks/CU -> 50% occupancy cap
__global__ __launch_bounds__(256) void mvpm_fused(const float* __restrict__ outp,
                                                  const float* __restrict__ tarp,
                                                  float* __restrict__ ws) {
    const int b = blockIdx.y;
    const int p = blockIdx.x * 256 + threadIdx.x;       // pixel index
    const float* ob = outp + (size_t)b * 134 * HW + p;
    const float* tb = tarp + (size_t)b * 101 * HW + p;
    const int lane = threadIdx.x & 63;
    const int wv = threadIdx.x >> 6;

    __shared__ float jacc[BN][7][4];    // per-j, per-component, per-wave
    __shared__ float red[11][4];

    // -- mask, mask-logit, nocs --
    const float m  = tb[3 * HW];
    const float ml = ob[3 * HW];
    const float a0 = ob[0], a1 = ob[HW], a2 = ob[2 * HW];
    const float b0 = tb[0], b1 = tb[HW], b2 = tb[2 * HW];

    const float bce = m * fminf(ml, 0.0f) + (1.0f - m) * fminf(-ml, 0.0f)
                      - __logf(1.0f + __expf(-fabsf(ml)));
    const float dn = sqrtf(sq(a0 - b0) + sq(a1 - b1) + sq(a2 - b2));
    const bool sel = m > 0.7f;
    const float mm = m * m;

    // -- skin CE: 18-channel batch --
    float x[18];
#pragma unroll
    for (int k = 0; k < 18; ++k) x[k] = ob[(100 + k) * HW];
    const float labf = tb[100 * HW];
    float mx = x[0];
#pragma unroll
    for (int k = 1; k < 18; ++k) mx = fmaxf(mx, x[k]);
    float se = 0.0f;
#pragma unroll
    for (int k = 0; k < 18; ++k) se += __expf(x[k] - mx);
    int lab = (int)labf; lab = lab < 0 ? 0 : (lab > 17 ? 17 : lab);
    float xl = x[0];
#pragma unroll
    for (int k = 1; k < 18; ++k) xl = (lab == k) ? x[k] : xl;
    const float skin = mx + __logf(se) - xl;

    // -- joint maps + score channels: 13 loads per j --
    float dsl = 0.0f, dsr = 0.0f;
#pragma unroll 2
    for (int j = 0; j < BN; ++j) {
        const int cl = (4 + 3 * j) * HW, cr = (52 + 3 * j) * HW;
        const float o0 = ob[cl], o1 = ob[cl + HW], o2 = ob[cl + 2 * HW];
        const float t0 = tb[cl], t1 = tb[cl + HW], t2 = tb[cl + 2 * HW];
        const float p0 = ob[cr], p1 = ob[cr + HW], p2 = ob[cr + 2 * HW];
        const float q0 = tb[cr], q1 = tb[cr + HW], q2 = tb[cr + 2 * HW];
        const float sc = ob[(118 + j) * HW];

        const float so0 = fsig(o0), so1 = fsig(o1), so2 = fsig(o2);
        const float sp0 = fsig(p0), sp1 = fsig(p1), sp2 = fsig(p2);
        dsl += sq(so0 - fsig(t0)) + sq(so1 - fsig(t1)) + sq(so2 - fsig(t2));
        dsr += sq(sp0 - fsig(q0)) + sq(sp1 - fsig(q1)) + sq(sp2 - fsig(q2));

        const float ss = fsig(sc);
        const float w2 = ss * mm;            // sig(score) * m^2
        float u[7];
        u[0] = ss * m;                       // S contribution
        u[1] = so0 * w2; u[2] = so1 * w2; u[3] = so2 * w2;
        u[4] = sp0 * w2; u[5] = sp1 * w2; u[6] = sp2 * w2;

#pragma unroll
        for (int off = 32; off; off >>= 1) {
#pragma unroll
            for (int i = 0; i < 7; ++i) u[i] += __shfl_xor(u[i], off, 64);
        }
        if (lane == 0) {
#pragma unroll
            for (int i = 0; i < 7; ++i) jacc[j][i][wv] = u[i];
        }
    }
    const float dnl = sqrtf(dsl), dnr = sqrtf(dsr);

    // -- 11 pixel-loss wave reductions --
    float v[11];
    v[0]  = bce;
    v[1]  = skin;
    v[2]  = sel ? dn : 0.0f;
    v[3]  = (sel && dn != 0.0f) ? 1.0f : 0.0f;
    v[4]  = dn;
    v[5]  = sel ? dnl : 0.0f;
    v[6]  = (sel && dnl != 0.0f) ? 1.0f : 0.0f;
    v[7]  = dnl;
    v[8]  = sel ? dnr : 0.0f;
    v[9]  = (sel && dnr != 0.0f) ? 1.0f : 0.0f;
    v[10] = dnr;

#pragma unroll
    for (int off = 32; off; off >>= 1) {
#pragma unroll
        for (int i = 0; i < 11; ++i) v[i] += __shfl_xor(v[i], off, 64);
    }
    if (lane == 0) {
#pragma unroll
        for (int i = 0; i < 11; ++i) red[i][wv] = v[i];
    }
    __syncthreads();

    const int t = threadIdx.x;
    if (t < 112) {                            // 16 j x 7 comps
        const int j = t / 7, c = t % 7;
        const float s = jacc[j][c][0] + jacc[j][c][1] + jacc[j][c][2] + jacc[j][c][3];
        atomicAdd(&ws[38 + (b * 16 + j) * 7 + c], s);
    } else if (t >= 128 && t < 139) {
        const int i = t - 128;
        const float s = red[i][0] + red[i][1] + red[i][2] + red[i][3];
        const int g = (i < 2) ? i : (2 + b * 9 + (i - 2));
        atomicAdd(&ws[g], s);
    }
}

// ---- finalize ------------------------------------------------------------
__global__ __launch_bounds__(64) void mvpm_fin(const float* __restrict__ ws,
                                               const float* __restrict__ tp,
                                               float* __restrict__ o) {
    const int t = threadIdx.x;      // (b, j)
    const int base = 38 + t * 7;

    float S = ws[base] + 1e-5f;
    float ln = 0.0f, rn = 0.0f;
#pragma unroll
    for (int c = 0; c < 3; ++c) {
        float pl = ws[base + 1 + c] / S;
        float tl = 1.0f / (1.0f + expf(-tp[t * 6 + c]));
        ln += (pl - tl) * (pl - tl);
        float pr = ws[base + 4 + c] / S;
        float tr = 1.0f / (1.0f + expf(-tp[t * 6 + 3 + c]));
        rn += (pr - tr) * (pr - tr);
    }
    ln = sqrtf(ln);
    rn = sqrtf(rn);
    float lsum = wred(ln);
    float rsum = wred(rn);

    if (t == 0) {
        float nocs = 0.0f, locm = 0.0f, rotm = 0.0f;
        for (int bb = 0; bb < 4; ++bb) {
            int ba = 2 + bb * 9;
            nocs += (ws[ba + 1] > 0.5f) ? ws[ba + 0] / ws[ba + 1] : ws[ba + 2] * (1.0f / HW);
            locm += (ws[ba + 4] > 0.5f) ? ws[ba + 3] / ws[ba + 4] : ws[ba + 5] * (1.0f / HW);
            rotm += (ws[ba + 7] > 0.5f) ? ws[ba + 6] / ws[ba + 7] : ws[ba + 8] * (1.0f / HW);
        }
        o[0] = nocs * 0.25f;                  // nocs_loss
        o[1] = -ws[0] / (4.0f * HW);          // mask_loss
        o[2] = lsum * (1.0f / 64.0f);         // loc_loss
        o[3] = locm * 0.25f;                  // loc_map_loss
        o[4] = rsum * (1.0f / 64.0f);         // rot_loss
        o[5] = rotm * 0.25f;                  // rot_map_loss
        o[6] = ws[1] / (4.0f * HW);           // skin_loss
    }
}

extern "C" void kernel_launch(void* const* d_in, const int* in_sizes, int n_in,
                              void* d_out, int out_size, void* d_ws, size_t ws_size,
                              hipStream_t stream) {
    const float* outp = (const float*)d_in[0];   // (4,134,256,256)
    const float* tarp = (const float*)d_in[1];   // (4,101,256,256)
    const float* tpos = (const float*)d_in[2];   // (4,16,6)
    float* o  = (float*)d_out;                   // 7 floats
    float* ws = (float*)d_ws;

    hipMemsetAsync(d_ws, 0, 486 * sizeof(float), stream);
    dim3 g(HW / 256, 4);                         // 1024 blocks, 1 px/thread
    mvpm_fused<<<g, 256, 0, stream>>>(outp, tarp, ws);
    mvpm_fin<<<1, 64, 0, stream>>>(ws, tpos, o);
}